// Round 1
// baseline (135.132 us; speedup 1.0000x reference)
//
#include <hip/hip_runtime.h>
#include <hip/hip_bf16.h>

#define C 128
#define HW 4096
#define NPOS 65536
#define K 1024
#define MB 128           // positions per block
#define NBLK (NPOS/MB)   // 512
#define RS 136           // zt padded row stride in bf16 elems (272 B)
#define RSB 320          // codebook image row stride BYTES (64B-aligned segments)
#define CHK 64           // codes per chunk
#define NCH (K/CHK)      // 16
#define CHB (CHK*RSB)    // 20480 bytes per chunk

#define ZQ_OFF 0
#define LOSS_OFF 8388608
#define IDX_OFF 8388609
#define COMMIT_OFF 8454145
#define CODE_OFF 8454146

#define WS_IMG_OFF 8192  // bf16 codebook image at d_ws + 8192, 1024*320 B

typedef __bf16 bf16x8 __attribute__((ext_vector_type(8)));
typedef float f32x4 __attribute__((ext_vector_type(4)));

// Build padded bf16 codebook image: row k = 128 bf16 (320B stride, so each
// 64B quarter-row is cache-line aligned), fp32 (||e_k||^2 + 1.0) at +256.
// Also zeroes the loss accumulator + completion ticket (replaces memset).
__global__ void vq_prep(const float* __restrict__ emb, unsigned char* __restrict__ img,
                        float* __restrict__ S) {
    int k = blockIdx.x;
    int l = threadIdx.x;            // 64 threads
    if (k == 0 && l == 0) { S[0] = 0.0f; ((unsigned int*)S)[1] = 0u; }
    float v0 = emb[k * C + l];
    float v1 = emb[k * C + 64 + l];
    __hip_bfloat16 h0 = __float2bfloat16(v0);
    __hip_bfloat16 h1 = __float2bfloat16(v1);
    unsigned short* row = (unsigned short*)(img + (size_t)k * RSB);
    row[l] = *(unsigned short*)&h0;
    row[64 + l] = *(unsigned short*)&h1;
    float s = v0 * v0 + v1 * v1;
    #pragma unroll
    for (int off = 32; off; off >>= 1) s += __shfl_down(s, off);
    if (l == 0) *(float*)(img + (size_t)k * RSB + 256) = s + 1.0f;
}

__global__ __launch_bounds__(256, 2)
void vq_main(const float* __restrict__ z, const float* __restrict__ emb,
             const unsigned char* __restrict__ img,
             float* __restrict__ out, float* __restrict__ S) {
    __shared__ unsigned short zt[MB * RS];        // 34816 B, z tile bf16, padded rows
    __shared__ unsigned int wbest[4][MB];         // 2048 B
    __shared__ unsigned short idxs[MB];           // 256 B
    __shared__ float lred[4];

    const int t = threadIdx.x;
    const int w = t >> 6;
    const int lane = t & 63;
    const int nn = lane & 15;      // MFMA: A row m / B col n / C col
    const int q = lane >> 4;       // quad

    const int blk = blockIdx.x;
    const int n0g = blk * MB;
    const int b = n0g >> 12;
    const int hw0 = n0g & (HW - 1);
    const float* zg = z + (size_t)b * C * HW + hw0;

    // stage z tile -> LDS bf16 [pos][c], row stride 272B
    {
        int pos = t & (MB - 1);
        int c0b = (t >> 7) * 64;
        #pragma unroll
        for (int i = 0; i < 16; ++i) {
            int c0 = c0b + i * 4;
            float f0 = zg[(size_t)(c0 + 0) * HW + pos];
            float f1 = zg[(size_t)(c0 + 1) * HW + pos];
            float f2 = zg[(size_t)(c0 + 2) * HW + pos];
            float f3 = zg[(size_t)(c0 + 3) * HW + pos];
            __hip_bfloat16 h0 = __float2bfloat16(f0), h1 = __float2bfloat16(f1),
                           h2 = __float2bfloat16(f2), h3 = __float2bfloat16(f3);
            ushort4 pk;
            pk.x = *(unsigned short*)&h0; pk.y = *(unsigned short*)&h1;
            pk.z = *(unsigned short*)&h2; pk.w = *(unsigned short*)&h3;
            *(ushort4*)&zt[pos * RS + c0] = pk;
        }
    }
    __syncthreads();   // zt ready; ONLY barrier before the reduction phase

    // A fragments in registers: 8 M-tiles x 4 K-steps, reused across ALL codes
    bf16x8 a[8][4];
    #pragma unroll
    for (int mt = 0; mt < 8; ++mt)
        #pragma unroll
        for (int ks = 0; ks < 4; ++ks)
            a[mt][ks] = *(bf16x8*)&zt[(mt * 16 + nn) * RS + ks * 32 + q * 8];

    unsigned int best[8][4];
    #pragma unroll
    for (int mt = 0; mt < 8; ++mt)
        #pragma unroll
        for (int r = 0; r < 4; ++r) best[mt][r] = 0xFFFFFFFFu;

    // B fragments straight from global (L2-resident image): wave w owns rows
    // w*16+nn of every chunk; lane reads 4x16B (quarter-rows) + the norm dword.
    // No LDS, no barriers -> waves slip freely; depth-2 register pipeline.
    const int row = w * 16 + nn;
    const unsigned char* pb = img + (size_t)row * RSB + q * 16;
    const unsigned char* pe = img + (size_t)row * RSB + 256;

    bf16x8 bcur[4];
    #pragma unroll
    for (int ks = 0; ks < 4; ++ks) bcur[ks] = *(const bf16x8*)(pb + ks * 64);
    float ecur = *(const float*)pe;

    #pragma unroll 2
    for (int ch = 0; ch < NCH; ++ch) {
        // prefetch next chunk's fragments into registers (last iter: reload cur, harmless)
        const int step = (ch + 1 < NCH) ? CHB : 0;
        bf16x8 bnxt[4];
        #pragma unroll
        for (int ks = 0; ks < 4; ++ks) bnxt[ks] = *(const bf16x8*)(pb + step + ks * 64);
        float enxt = *(const float*)(pe + step);

        const unsigned int code = (unsigned int)(ch * CHK + row);

        f32x4 acc[8];
        #pragma unroll
        for (int mt = 0; mt < 8; ++mt) acc[mt] = (f32x4){0.f, 0.f, 0.f, 0.f};
        #pragma unroll
        for (int ks = 0; ks < 4; ++ks)
            #pragma unroll
            for (int mt = 0; mt < 8; ++mt)
                acc[mt] = __builtin_amdgcn_mfma_f32_16x16x32_bf16(a[mt][ks], bcur[ks], acc[mt], 0, 0, 0);

        // packed argmin: score' = (enorm+1) - 2*dot  (always in (0.68,1.32) > 0),
        // clear low 10 mantissa bits, OR in code; u32 min == float min + tie-low.
        #pragma unroll
        for (int mt = 0; mt < 8; ++mt)
            #pragma unroll
            for (int r = 0; r < 4; ++r) {
                float s = fmaf(acc[mt][r], -2.0f, ecur);
                unsigned int u = (__float_as_uint(s) & ~1023u) | code;
                best[mt][r] = min(best[mt][r], u);
            }

        #pragma unroll
        for (int ks = 0; ks < 4; ++ks) bcur[ks] = bnxt[ks];
        ecur = enxt;
        pb += CHB; pe += CHB;
    }

    // in-wave reduce over the 16 code-columns (xor lanes 1,2,4,8 stay in quad)
    #pragma unroll
    for (int mt = 0; mt < 8; ++mt)
        #pragma unroll
        for (int r = 0; r < 4; ++r) {
            unsigned int v = best[mt][r];
            v = min(v, (unsigned int)__shfl_xor((int)v, 1));
            v = min(v, (unsigned int)__shfl_xor((int)v, 2));
            v = min(v, (unsigned int)__shfl_xor((int)v, 4));
            v = min(v, (unsigned int)__shfl_xor((int)v, 8));
            if (nn == 0) wbest[w][mt * 16 + q * 4 + r] = v;   // pos-local
        }
    __syncthreads();

    if (t < MB) {
        unsigned int v = min(min(wbest[0][t], wbest[1][t]), min(wbest[2][t], wbest[3][t]));
        unsigned int code = v & 1023u;
        idxs[t] = (unsigned short)code;
        out[IDX_OFF + n0g + t] = (float)code;
    }
    __syncthreads();

    // epilogue: exact fp32 gather of chosen code rows, z_q store, loss
    {
        int pos = t & (MB - 1);
        int c0b = (t >> 7) * 64;
        int myidx = idxs[pos];
        const float* erow = emb + (size_t)myidx * C;
        float* og = out + ZQ_OFF + (size_t)b * C * HW + hw0;
        float ls = 0.f;
        #pragma unroll
        for (int i = 0; i < 16; ++i) {
            int c0 = c0b + i * 4;
            float4 ev = *(const float4*)&erow[c0];
            ushort4 zz = *(ushort4*)&zt[pos * RS + c0];
            float z0 = __uint_as_float((unsigned int)zz.x << 16);
            float z1 = __uint_as_float((unsigned int)zz.y << 16);
            float z2 = __uint_as_float((unsigned int)zz.z << 16);
            float z3 = __uint_as_float((unsigned int)zz.w << 16);
            float d0 = z0 - ev.x, d1 = z1 - ev.y, d2 = z2 - ev.z, d3 = z3 - ev.w;
            ls += d0 * d0 + d1 * d1 + d2 * d2 + d3 * d3;
            og[(size_t)(c0 + 0) * HW + pos] = ev.x;
            og[(size_t)(c0 + 1) * HW + pos] = ev.y;
            og[(size_t)(c0 + 2) * HW + pos] = ev.z;
            og[(size_t)(c0 + 3) * HW + pos] = ev.w;
        }
        #pragma unroll
        for (int off = 32; off; off >>= 1) ls += __shfl_down(ls, off);
        if (lane == 0) lred[w] = ls;
    }
    __syncthreads();

    // fused finalization: last block to retire writes the scalar outputs
    if (t == 0) {
        float bs = lred[0] + lred[1] + lred[2] + lred[3];
        atomicAdd(S, bs);
        __threadfence();
        unsigned int old = atomicAdd((unsigned int*)S + 1, 1u);
        if (old == NBLK - 1) {
            __threadfence();
            float s = atomicAdd(S, 0.0f);   // RMW read of the coherent total
            out[LOSS_OFF] = 1.25f * s;
            out[COMMIT_OFF] = 0.25f * s;
            out[CODE_OFF] = s;
        }
    }
}

extern "C" void kernel_launch(void* const* d_in, const int* in_sizes, int n_in,
                              void* d_out, int out_size, void* d_ws, size_t ws_size,
                              hipStream_t stream) {
    const float* z = (const float*)d_in[0];
    const float* emb = (const float*)d_in[1];
    float* out = (float*)d_out;
    float* S = (float*)d_ws;
    unsigned char* img = (unsigned char*)d_ws + WS_IMG_OFF;   // needs ~336 KB of ws

    vq_prep<<<K, 64, 0, stream>>>(emb, img, S);
    vq_main<<<NBLK, 256, 0, stream>>>(z, emb, img, out, S);
}

// Round 2
// 130.025 us; speedup vs baseline: 1.0393x; 1.0393x over previous
//
#include <hip/hip_runtime.h>
#include <hip/hip_bf16.h>

#define C 128
#define HW 4096
#define NPOS 65536
#define K 1024
#define MB 128           // positions per block
#define NBLK (NPOS/MB)   // 512
#define RS 136           // padded row stride in bf16 elems (272 B)
#define RSB 272          // row stride bytes
#define CHK 64           // codes per chunk
#define NCH (K/CHK)      // 16
#define CHB (CHK*RSB)    // 17408 bytes per chunk

#define ZQ_OFF 0
#define LOSS_OFF 8388608
#define IDX_OFF 8388609
#define COMMIT_OFF 8454145
#define CODE_OFF 8454146

#define WS_IMG_OFF 8192  // bf16 codebook image at d_ws + 8192, 1024*272 B

typedef __bf16 bf16x8 __attribute__((ext_vector_type(8)));
typedef float f32x4 __attribute__((ext_vector_type(4)));

// Build padded bf16 codebook image: row k = 128 bf16 (272B stride),
// fp32 (||e_k||^2 + 1.0) stored at row byte offset 256 (in the pad).
// Block 0 also zeroes the loss accumulator + completion ticket.
__global__ void vq_prep(const float* __restrict__ emb, unsigned char* __restrict__ img,
                        float* __restrict__ S) {
    int k = blockIdx.x;
    int l = threadIdx.x;            // 64 threads
    if (k == 0 && l == 0) { S[0] = 0.0f; ((unsigned int*)S)[1] = 0u; }
    float v0 = emb[k * C + l];
    float v1 = emb[k * C + 64 + l];
    __hip_bfloat16 h0 = __float2bfloat16(v0);
    __hip_bfloat16 h1 = __float2bfloat16(v1);
    unsigned short* row = (unsigned short*)(img + (size_t)k * RSB);
    row[l] = *(unsigned short*)&h0;
    row[64 + l] = *(unsigned short*)&h1;
    float s = v0 * v0 + v1 * v1;
    #pragma unroll
    for (int off = 32; off; off >>= 1) s += __shfl_down(s, off);
    if (l == 0) *(float*)(img + (size_t)k * RSB + 256) = s + 1.0f;
}

// LDS (72 KB) caps residency at 2 blocks/CU = 2 waves/SIMD regardless of
// VGPRs, and grid=512 = 2 blocks/CU anyway -> pin waves/EU to 2 so the
// allocator uses the full 256-VGPR budget and keeps all 32 A-fragments
// resident instead of re-reading them from LDS every chunk.
__global__ __attribute__((amdgpu_flat_work_group_size(256, 256), amdgpu_waves_per_eu(2, 2)))
void vq_main(const float* __restrict__ z, const float* __restrict__ emb,
             const unsigned char* __restrict__ img,
             float* __restrict__ out, float* __restrict__ S) {
    __shared__ unsigned short zt[MB * RS];        // 34816 B, z tile bf16, padded rows
    __shared__ unsigned short bbuf[2][CHK * RS];  // 2 x 17408 B, codebook chunks
    __shared__ unsigned int wbest[4][MB];         // 2048 B
    __shared__ unsigned short idxs[MB];           // 256 B
    __shared__ float lred[4];

    const int t = threadIdx.x;
    const int w = t >> 6;
    const int lane = t & 63;
    const int nn = lane & 15;      // MFMA: A row m / B col n / C col
    const int q = lane >> 4;       // quad

    const int blk = blockIdx.x;
    const int n0g = blk * MB;
    const int b = n0g >> 12;
    const int hw0 = n0g & (HW - 1);
    const float* zg = z + (size_t)b * C * HW + hw0;

    // async stage chunk 0 of codebook image (17 x 1KB, split across waves)
    for (int j = w; j < 17; j += 4) {
        __builtin_amdgcn_global_load_lds(
            (const __attribute__((address_space(1))) unsigned int*)(img + j * 1024 + lane * 16),
            (__attribute__((address_space(3))) unsigned int*)((unsigned char*)bbuf[0] + j * 1024),
            16, 0, 0);
    }

    // stage z tile -> LDS bf16 [pos][c], row stride 272B
    {
        int pos = t & (MB - 1);
        int c0b = (t >> 7) * 64;
        #pragma unroll
        for (int i = 0; i < 16; ++i) {
            int c0 = c0b + i * 4;
            float f0 = zg[(size_t)(c0 + 0) * HW + pos];
            float f1 = zg[(size_t)(c0 + 1) * HW + pos];
            float f2 = zg[(size_t)(c0 + 2) * HW + pos];
            float f3 = zg[(size_t)(c0 + 3) * HW + pos];
            __hip_bfloat16 h0 = __float2bfloat16(f0), h1 = __float2bfloat16(f1),
                           h2 = __float2bfloat16(f2), h3 = __float2bfloat16(f3);
            ushort4 pk;
            pk.x = *(unsigned short*)&h0; pk.y = *(unsigned short*)&h1;
            pk.z = *(unsigned short*)&h2; pk.w = *(unsigned short*)&h3;
            *(ushort4*)&zt[pos * RS + c0] = pk;
        }
    }
    __syncthreads();   // covers zt ds_writes AND chunk-0 global_load_lds (vmcnt drain)

    // A fragments in registers: 8 M-tiles x 4 K-steps, reused across ALL codes
    bf16x8 a[8][4];
    #pragma unroll
    for (int mt = 0; mt < 8; ++mt)
        #pragma unroll
        for (int ks = 0; ks < 4; ++ks)
            a[mt][ks] = *(bf16x8*)&zt[(mt * 16 + nn) * RS + ks * 32 + q * 8];

    unsigned int best[8][4];
    #pragma unroll
    for (int mt = 0; mt < 8; ++mt)
        #pragma unroll
        for (int r = 0; r < 4; ++r) best[mt][r] = 0xFFFFFFFFu;

    for (int ch = 0; ch < NCH; ++ch) {
        const int p = ch & 1;
        if (ch + 1 < NCH) {   // prefetch next chunk into other buffer
            const unsigned char* src = img + (size_t)(ch + 1) * CHB;
            for (int j = w; j < 17; j += 4) {
                __builtin_amdgcn_global_load_lds(
                    (const __attribute__((address_space(1))) unsigned int*)(src + j * 1024 + lane * 16),
                    (__attribute__((address_space(3))) unsigned int*)((unsigned char*)bbuf[p ^ 1] + j * 1024),
                    16, 0, 0);
            }
        }
        const unsigned short* bb = bbuf[p];
        const int row = w * 16 + nn;          // wave w owns 16 codes of this chunk
        bf16x8 bf[4];
        #pragma unroll
        for (int ks = 0; ks < 4; ++ks)
            bf[ks] = *(bf16x8*)&bb[row * RS + ks * 32 + q * 8];
        const float en1 = *(const float*)&bb[row * RS + 128];   // ||e||^2 + 1 (fp32)
        const unsigned int code = (unsigned int)(ch * CHK + row);

        f32x4 acc[8];
        #pragma unroll
        for (int mt = 0; mt < 8; ++mt) acc[mt] = (f32x4){0.f, 0.f, 0.f, 0.f};
        #pragma unroll
        for (int ks = 0; ks < 4; ++ks)
            #pragma unroll
            for (int mt = 0; mt < 8; ++mt)
                acc[mt] = __builtin_amdgcn_mfma_f32_16x16x32_bf16(a[mt][ks], bf[ks], acc[mt], 0, 0, 0);

        // packed argmin: score' = (enorm+1) - 2*dot  (always in (0.68,1.32) > 0),
        // clear low 10 mantissa bits, OR in code; u32 min == float min + tie-low.
        #pragma unroll
        for (int mt = 0; mt < 8; ++mt)
            #pragma unroll
            for (int r = 0; r < 4; ++r) {
                float s = fmaf(acc[mt][r], -2.0f, en1);
                unsigned int u = (__float_as_uint(s) & ~1023u) | code;
                best[mt][r] = min(best[mt][r], u);
            }
        __syncthreads();   // chunk consumed by all waves; prefetched data now visible
    }

    // in-wave reduce over the 16 code-columns (xor lanes 1,2,4,8 stay in quad)
    #pragma unroll
    for (int mt = 0; mt < 8; ++mt)
        #pragma unroll
        for (int r = 0; r < 4; ++r) {
            unsigned int v = best[mt][r];
            v = min(v, (unsigned int)__shfl_xor((int)v, 1));
            v = min(v, (unsigned int)__shfl_xor((int)v, 2));
            v = min(v, (unsigned int)__shfl_xor((int)v, 4));
            v = min(v, (unsigned int)__shfl_xor((int)v, 8));
            if (nn == 0) wbest[w][mt * 16 + q * 4 + r] = v;   // pos-local
        }
    __syncthreads();

    if (t < MB) {
        unsigned int v = min(min(wbest[0][t], wbest[1][t]), min(wbest[2][t], wbest[3][t]));
        unsigned int code = v & 1023u;
        idxs[t] = (unsigned short)code;
        out[IDX_OFF + n0g + t] = (float)code;
    }
    __syncthreads();

    // epilogue: exact fp32 gather of chosen code rows, z_q store, loss
    {
        int pos = t & (MB - 1);
        int c0b = (t >> 7) * 64;
        int myidx = idxs[pos];
        const float* erow = emb + (size_t)myidx * C;
        float* og = out + ZQ_OFF + (size_t)b * C * HW + hw0;
        float ls = 0.f;
        #pragma unroll
        for (int i = 0; i < 16; ++i) {
            int c0 = c0b + i * 4;
            float4 ev = *(const float4*)&erow[c0];
            ushort4 zz = *(ushort4*)&zt[pos * RS + c0];
            float z0 = __uint_as_float((unsigned int)zz.x << 16);
            float z1 = __uint_as_float((unsigned int)zz.y << 16);
            float z2 = __uint_as_float((unsigned int)zz.z << 16);
            float z3 = __uint_as_float((unsigned int)zz.w << 16);
            float d0 = z0 - ev.x, d1 = z1 - ev.y, d2 = z2 - ev.z, d3 = z3 - ev.w;
            ls += d0 * d0 + d1 * d1 + d2 * d2 + d3 * d3;
            og[(size_t)(c0 + 0) * HW + pos] = ev.x;
            og[(size_t)(c0 + 1) * HW + pos] = ev.y;
            og[(size_t)(c0 + 2) * HW + pos] = ev.z;
            og[(size_t)(c0 + 3) * HW + pos] = ev.w;
        }
        #pragma unroll
        for (int off = 32; off; off >>= 1) ls += __shfl_down(ls, off);
        if (lane == 0) lred[w] = ls;
    }
    __syncthreads();

    // fused finalization: last block to retire writes the scalar outputs
    if (t == 0) {
        float bs = lred[0] + lred[1] + lred[2] + lred[3];
        atomicAdd(S, bs);
        __threadfence();
        unsigned int old = atomicAdd((unsigned int*)S + 1, 1u);
        if (old == NBLK - 1) {
            __threadfence();
            float s = atomicAdd(S, 0.0f);   // RMW read of the coherent total
            out[LOSS_OFF] = 1.25f * s;
            out[COMMIT_OFF] = 0.25f * s;
            out[CODE_OFF] = s;
        }
    }
}

extern "C" void kernel_launch(void* const* d_in, const int* in_sizes, int n_in,
                              void* d_out, int out_size, void* d_ws, size_t ws_size,
                              hipStream_t stream) {
    const float* z = (const float*)d_in[0];
    const float* emb = (const float*)d_in[1];
    float* out = (float*)d_out;
    float* S = (float*)d_ws;
    unsigned char* img = (unsigned char*)d_ws + WS_IMG_OFF;   // needs ~287 KB of ws

    vq_prep<<<K, 64, 0, stream>>>(emb, img, S);
    vq_main<<<NBLK, 256, 0, stream>>>(z, emb, img, out, S);
}

// Round 3
// 115.229 us; speedup vs baseline: 1.1727x; 1.1284x over previous
//
#include <hip/hip_runtime.h>
#include <hip/hip_bf16.h>

#define C 128
#define HW 4096
#define NPOS 65536
#define K 1024
#define MB 128           // positions per block
#define NBLK (NPOS/MB)   // 512
#define RS 136           // padded row stride in bf16 elems (272 B)
#define RSB 272          // row stride bytes
#define CHK 64           // codes per chunk
#define NCH (K/CHK)      // 16
#define CHB (CHK*RSB)    // 17408 bytes per chunk

#define ZQ_OFF 0
#define LOSS_OFF 8388608
#define IDX_OFF 8388609
#define COMMIT_OFF 8454145
#define CODE_OFF 8454146

#define WS_IMG_OFF 8192  // bf16 codebook image at d_ws + 8192, 1024*272 B

typedef __bf16 bf16x8 __attribute__((ext_vector_type(8)));
typedef float f32x4 __attribute__((ext_vector_type(4)));

// Build padded bf16 codebook image: row k = 128 bf16 (272B stride),
// fp32 (||e_k||^2 + 1.0) stored at row byte offset 256 (in the pad).
// Block 0 also zeroes the loss accumulator (replaces the memset dispatch).
__global__ void vq_prep(const float* __restrict__ emb, unsigned char* __restrict__ img,
                        float* __restrict__ S) {
    int k = blockIdx.x;
    int l = threadIdx.x;            // 64 threads
    if (k == 0 && l == 0) S[0] = 0.0f;
    float v0 = emb[k * C + l];
    float v1 = emb[k * C + 64 + l];
    __hip_bfloat16 h0 = __float2bfloat16(v0);
    __hip_bfloat16 h1 = __float2bfloat16(v1);
    unsigned short* row = (unsigned short*)(img + (size_t)k * RSB);
    row[l] = *(unsigned short*)&h0;
    row[64 + l] = *(unsigned short*)&h1;
    float s = v0 * v0 + v1 * v1;
    #pragma unroll
    for (int off = 32; off; off >>= 1) s += __shfl_down(s, off);
    if (l == 0) *(float*)(img + (size_t)k * RSB + 256) = s + 1.0f;
}

// Wave decomposition 2M x 2N: wave (wm,wn) owns 64 positions x 32 codes.
// Per-wave A-tile = 64 pos x 128 ch = 64 VGPRs -> stays register-resident
// across the whole chunk loop (the old 1x4 split needed 128 VGPRs and the
// allocator rematerialized A from LDS every chunk -> LDS-pipe-bound).
__global__ __launch_bounds__(256, 2)
void vq_main(const float* __restrict__ z, const float* __restrict__ emb,
             const unsigned char* __restrict__ img,
             float* __restrict__ out, float* __restrict__ S) {
    __shared__ unsigned short zt[MB * RS];        // 34816 B, z tile bf16, padded rows
    __shared__ unsigned short bbuf[2][CHK * RS];  // 2 x 17408 B, codebook chunks
    __shared__ unsigned int wbest[2][MB];         // 1024 B (indexed by wn)
    __shared__ unsigned short idxs[MB];           // 256 B
    __shared__ float lred[4];

    const int t = threadIdx.x;
    const int w = t >> 6;
    const int lane = t & 63;
    const int nn = lane & 15;      // MFMA: A row m / B col n / C col
    const int q = lane >> 4;       // quad
    const int wm = w >> 1;         // M-half: positions wm*64..wm*64+63
    const int wn = w & 1;          // N-half: codes wn*32..wn*32+31 of each chunk

    const int blk = blockIdx.x;
    const int n0g = blk * MB;
    const int b = n0g >> 12;
    const int hw0 = n0g & (HW - 1);
    const float* zg = z + (size_t)b * C * HW + hw0;

    // async stage chunk 0 of codebook image (17 x 1KB, split across waves)
    for (int j = w; j < 17; j += 4) {
        __builtin_amdgcn_global_load_lds(
            (const __attribute__((address_space(1))) unsigned int*)(img + j * 1024 + lane * 16),
            (__attribute__((address_space(3))) unsigned int*)((unsigned char*)bbuf[0] + j * 1024),
            16, 0, 0);
    }

    // stage z tile -> LDS bf16 [pos][c], row stride 272B
    {
        int pos = t & (MB - 1);
        int c0b = (t >> 7) * 64;
        #pragma unroll
        for (int i = 0; i < 16; ++i) {
            int c0 = c0b + i * 4;
            float f0 = zg[(size_t)(c0 + 0) * HW + pos];
            float f1 = zg[(size_t)(c0 + 1) * HW + pos];
            float f2 = zg[(size_t)(c0 + 2) * HW + pos];
            float f3 = zg[(size_t)(c0 + 3) * HW + pos];
            __hip_bfloat16 h0 = __float2bfloat16(f0), h1 = __float2bfloat16(f1),
                           h2 = __float2bfloat16(f2), h3 = __float2bfloat16(f3);
            ushort4 pk;
            pk.x = *(unsigned short*)&h0; pk.y = *(unsigned short*)&h1;
            pk.z = *(unsigned short*)&h2; pk.w = *(unsigned short*)&h3;
            *(ushort4*)&zt[pos * RS + c0] = pk;
        }
    }
    __syncthreads();   // covers zt ds_writes AND chunk-0 global_load_lds (vmcnt drain)

    // A fragments in registers: 4 M-tiles x 4 K-steps = 64 VGPRs, resident
    bf16x8 a[4][4];
    #pragma unroll
    for (int mt = 0; mt < 4; ++mt)
        #pragma unroll
        for (int ks = 0; ks < 4; ++ks)
            a[mt][ks] = *(bf16x8*)&zt[(wm * 64 + mt * 16 + nn) * RS + ks * 32 + q * 8];

    unsigned int best[4][4];
    #pragma unroll
    for (int mt = 0; mt < 4; ++mt)
        #pragma unroll
        for (int r = 0; r < 4; ++r) best[mt][r] = 0xFFFFFFFFu;

    for (int ch = 0; ch < NCH; ++ch) {
        const int p = ch & 1;
        if (ch + 1 < NCH) {   // prefetch next chunk into other buffer
            const unsigned char* src = img + (size_t)(ch + 1) * CHB;
            for (int j = w; j < 17; j += 4) {
                __builtin_amdgcn_global_load_lds(
                    (const __attribute__((address_space(1))) unsigned int*)(src + j * 1024 + lane * 16),
                    (__attribute__((address_space(3))) unsigned int*)((unsigned char*)bbuf[p ^ 1] + j * 1024),
                    16, 0, 0);
            }
        }
        const unsigned short* bb = bbuf[p];

        // wave's 32 codes: two 16-wide N-tiles
        bf16x8 bf[2][4];
        float en[2];
        #pragma unroll
        for (int nt = 0; nt < 2; ++nt) {
            const int row = wn * 32 + nt * 16 + nn;
            #pragma unroll
            for (int ks = 0; ks < 4; ++ks)
                bf[nt][ks] = *(bf16x8*)&bb[row * RS + ks * 32 + q * 8];
            en[nt] = *(const float*)&bb[row * RS + 128];   // ||e||^2 + 1 (fp32)
        }
        const unsigned int code0 = (unsigned int)(ch * CHK + wn * 32 + nn);

        f32x4 acc[4][2];
        #pragma unroll
        for (int mt = 0; mt < 4; ++mt)
            #pragma unroll
            for (int nt = 0; nt < 2; ++nt) acc[mt][nt] = (f32x4){0.f, 0.f, 0.f, 0.f};
        #pragma unroll
        for (int ks = 0; ks < 4; ++ks)
            #pragma unroll
            for (int mt = 0; mt < 4; ++mt)
                #pragma unroll
                for (int nt = 0; nt < 2; ++nt)
                    acc[mt][nt] = __builtin_amdgcn_mfma_f32_16x16x32_bf16(a[mt][ks], bf[nt][ks], acc[mt][nt], 0, 0, 0);

        // packed argmin: score' = (enorm+1) - 2*dot (always ~1.0 > 0),
        // clear low 10 mantissa bits, OR in code; u32 min == float min + tie-low.
        #pragma unroll
        for (int mt = 0; mt < 4; ++mt)
            #pragma unroll
            for (int r = 0; r < 4; ++r) {
                float s0 = fmaf(acc[mt][0][r], -2.0f, en[0]);
                float s1 = fmaf(acc[mt][1][r], -2.0f, en[1]);
                unsigned int u0 = (__float_as_uint(s0) & ~1023u) | code0;
                unsigned int u1 = (__float_as_uint(s1) & ~1023u) | (code0 + 16u);
                best[mt][r] = min(best[mt][r], min(u0, u1));
            }
        __syncthreads();   // chunk consumed by all waves; prefetched data now visible
    }

    // in-wave reduce over the 16 code-columns (xor lanes 1,2,4,8 stay in quad)
    #pragma unroll
    for (int mt = 0; mt < 4; ++mt)
        #pragma unroll
        for (int r = 0; r < 4; ++r) {
            unsigned int v = best[mt][r];
            v = min(v, (unsigned int)__shfl_xor((int)v, 1));
            v = min(v, (unsigned int)__shfl_xor((int)v, 2));
            v = min(v, (unsigned int)__shfl_xor((int)v, 4));
            v = min(v, (unsigned int)__shfl_xor((int)v, 8));
            if (nn == 0) wbest[wn][wm * 64 + mt * 16 + q * 4 + r] = v;
        }
    __syncthreads();

    if (t < MB) {
        unsigned int v = min(wbest[0][t], wbest[1][t]);
        unsigned int code = v & 1023u;
        idxs[t] = (unsigned short)code;
        out[IDX_OFF + n0g + t] = (float)code;
    }
    __syncthreads();

    // epilogue: exact fp32 gather of chosen code rows, z_q store, loss
    {
        int pos = t & (MB - 1);
        int c0b = (t >> 7) * 64;
        int myidx = idxs[pos];
        const float* erow = emb + (size_t)myidx * C;
        float* og = out + ZQ_OFF + (size_t)b * C * HW + hw0;
        float ls = 0.f;
        #pragma unroll
        for (int i = 0; i < 16; ++i) {
            int c0 = c0b + i * 4;
            float4 ev = *(const float4*)&erow[c0];
            ushort4 zz = *(ushort4*)&zt[pos * RS + c0];
            float z0 = __uint_as_float((unsigned int)zz.x << 16);
            float z1 = __uint_as_float((unsigned int)zz.y << 16);
            float z2 = __uint_as_float((unsigned int)zz.z << 16);
            float z3 = __uint_as_float((unsigned int)zz.w << 16);
            float d0 = z0 - ev.x, d1 = z1 - ev.y, d2 = z2 - ev.z, d3 = z3 - ev.w;
            ls += d0 * d0 + d1 * d1 + d2 * d2 + d3 * d3;
            og[(size_t)(c0 + 0) * HW + pos] = ev.x;
            og[(size_t)(c0 + 1) * HW + pos] = ev.y;
            og[(size_t)(c0 + 2) * HW + pos] = ev.z;
            og[(size_t)(c0 + 3) * HW + pos] = ev.w;
        }
        #pragma unroll
        for (int off = 32; off; off >>= 1) ls += __shfl_down(ls, off);
        if (lane == 0) lred[w] = ls;
    }
    __syncthreads();
    if (t == 0) atomicAdd(S, lred[0] + lred[1] + lred[2] + lred[3]);
}

__global__ void vq_final(const float* __restrict__ S, float* __restrict__ out) {
    float s = *S;
    out[LOSS_OFF] = 1.25f * s;
    out[COMMIT_OFF] = 0.25f * s;
    out[CODE_OFF] = s;
}

extern "C" void kernel_launch(void* const* d_in, const int* in_sizes, int n_in,
                              void* d_out, int out_size, void* d_ws, size_t ws_size,
                              hipStream_t stream) {
    const float* z = (const float*)d_in[0];
    const float* emb = (const float*)d_in[1];
    float* out = (float*)d_out;
    float* S = (float*)d_ws;
    unsigned char* img = (unsigned char*)d_ws + WS_IMG_OFF;   // needs ~287 KB of ws

    vq_prep<<<K, 64, 0, stream>>>(emb, img, S);
    vq_main<<<NBLK, 256, 0, stream>>>(z, emb, img, out, S);
    vq_final<<<1, 1, 0, stream>>>(S, out);
}

// Round 4
// 113.413 us; speedup vs baseline: 1.1915x; 1.0160x over previous
//
#include <hip/hip_runtime.h>
#include <hip/hip_bf16.h>

#define C 128
#define HW 4096
#define NPOS 65536
#define K 1024
#define MB 128           // positions per block
#define NBLK (NPOS/MB)   // 512
#define RS 136           // zt padded row stride in bf16 elems (272 B)
#define CHK 64           // codes per chunk
#define NCH (K/CHK)      // 16
#define CHB 16384        // chunk bytes: 64 rows x 256 B (swizzled, no pad)
#define NRM_OFF 262144   // norms array offset within img (4 KB fp32)

#define ZQ_OFF 0
#define LOSS_OFF 8388608
#define IDX_OFF 8388609
#define COMMIT_OFF 8454145
#define CODE_OFF 8454146

#define WS_IMG_OFF 8192  // codebook image at d_ws + 8192: 256 KB rows + 4 KB norms

typedef __bf16 bf16x8 __attribute__((ext_vector_type(8)));
typedef float f32x4 __attribute__((ext_vector_type(4)));

// Codebook image, chunked + XOR-swizzled: chunk c holds rows [c*64, c*64+64)
// at 256 B/row; byte offset within chunk = (r*256 + col) ^ ((r&7)<<4).
// Swizzle keeps ds_read_b128 at 2-way banking despite the 256B stride; image
// is PRE-swizzled in global so global_load_lds stays a linear copy (m104/m173).
// Norms ||e||^2+1 live in a separate fp32 table at NRM_OFF.
__global__ void vq_prep(const float* __restrict__ emb, unsigned char* __restrict__ img,
                        float* __restrict__ S) {
    int k = blockIdx.x;
    int l = threadIdx.x;            // 64 threads; lane l handles channels 2l, 2l+1
    if (k == 0 && l == 0) S[0] = 0.0f;
    float v0 = emb[k * C + 2 * l];
    float v1 = emb[k * C + 2 * l + 1];
    __hip_bfloat16 h0 = __float2bfloat16(v0);
    __hip_bfloat16 h1 = __float2bfloat16(v1);
    unsigned int pk = ((unsigned int)*(unsigned short*)&h1 << 16) | *(unsigned short*)&h0;
    int r = k & 63;
    unsigned int lin = (unsigned int)r * 256u + (unsigned int)l * 4u;
    unsigned int swz = lin ^ ((unsigned int)(r & 7) << 4);
    *(unsigned int*)(img + (size_t)(k >> 6) * CHB + swz) = pk;
    float s = v0 * v0 + v1 * v1;
    #pragma unroll
    for (int off = 32; off; off >>= 1) s += __shfl_down(s, off);
    if (l == 0) *(float*)(img + NRM_OFF + (size_t)k * 4) = s + 1.0f;
}

// 2M x 2N wave split (A resident in 64 VGPRs, proven r3). Main loop uses raw
// s_barrier + counted vmcnt (T3/T4): no vmcnt(0) drain ever in steady state,
// so codebook prefetch latency hides under MFMA instead of convoying 8 waves.
__global__ __launch_bounds__(256, 2)
void vq_main(const float* __restrict__ z, const float* __restrict__ emb,
             const unsigned char* __restrict__ img,
             float* __restrict__ out, float* __restrict__ S) {
    __shared__ __align__(16) unsigned short zt[MB * RS];     // 34816 B
    __shared__ __align__(16) unsigned short bbuf[2][CHB/2];  // 2 x 16384 B
    __shared__ __align__(16) float norm_lds[K];              // 4096 B
    __shared__ unsigned int wbest[2][MB];                    // 1024 B
    __shared__ unsigned short idxs[MB];                      // 256 B
    __shared__ float lred[4];
    // total ~73 KB -> 2 blocks/CU

    const int t = threadIdx.x;
    const int w = t >> 6;
    const int lane = t & 63;
    const int nn = lane & 15;      // MFMA: A row m / B col n / C col
    const int q = lane >> 4;       // quad
    const int wm = w >> 1;         // M-half: positions wm*64..+63
    const int wn = w & 1;          // N-half: codes wn*32..+31 of each chunk

    const int blk = blockIdx.x;
    const int n0g = blk * MB;
    const int b = n0g >> 12;
    const int hw0 = n0g & (HW - 1);
    const float* zg = z + (size_t)b * C * HW + hw0;

    // prologue staging: chunk0 -> bbuf[0], norms, chunk1 -> bbuf[1] (async)
    #pragma unroll
    for (int i = 0; i < 4; ++i) {
        int j = w * 4 + i;
        __builtin_amdgcn_global_load_lds(
            (const __attribute__((address_space(1))) unsigned int*)(img + j * 1024 + lane * 16),
            (__attribute__((address_space(3))) unsigned int*)((unsigned char*)bbuf[0] + j * 1024),
            16, 0, 0);
    }
    __builtin_amdgcn_global_load_lds(
        (const __attribute__((address_space(1))) unsigned int*)(img + NRM_OFF + w * 1024 + lane * 16),
        (__attribute__((address_space(3))) unsigned int*)((unsigned char*)norm_lds + w * 1024),
        16, 0, 0);
    #pragma unroll
    for (int i = 0; i < 4; ++i) {
        int j = w * 4 + i;
        __builtin_amdgcn_global_load_lds(
            (const __attribute__((address_space(1))) unsigned int*)(img + CHB + j * 1024 + lane * 16),
            (__attribute__((address_space(3))) unsigned int*)((unsigned char*)bbuf[1] + j * 1024),
            16, 0, 0);
    }

    // stage z tile -> LDS bf16 [pos][c], row stride 272B
    {
        int pos = t & (MB - 1);
        int c0b = (t >> 7) * 64;
        #pragma unroll
        for (int i = 0; i < 16; ++i) {
            int c0 = c0b + i * 4;
            float f0 = zg[(size_t)(c0 + 0) * HW + pos];
            float f1 = zg[(size_t)(c0 + 1) * HW + pos];
            float f2 = zg[(size_t)(c0 + 2) * HW + pos];
            float f3 = zg[(size_t)(c0 + 3) * HW + pos];
            __hip_bfloat16 h0 = __float2bfloat16(f0), h1 = __float2bfloat16(f1),
                           h2 = __float2bfloat16(f2), h3 = __float2bfloat16(f3);
            ushort4 pk;
            pk.x = *(unsigned short*)&h0; pk.y = *(unsigned short*)&h1;
            pk.z = *(unsigned short*)&h2; pk.w = *(unsigned short*)&h3;
            *(ushort4*)&zt[pos * RS + c0] = pk;
        }
    }
    __syncthreads();   // prologue: full drain once; bbuf0/1, norms, zt all valid

    // A fragments: 4 M-tiles x 4 K-steps = 64 VGPRs, resident across chunks
    bf16x8 a[4][4];
    #pragma unroll
    for (int mt = 0; mt < 4; ++mt)
        #pragma unroll
        for (int ks = 0; ks < 4; ++ks)
            a[mt][ks] = *(bf16x8*)&zt[(wm * 64 + mt * 16 + nn) * RS + ks * 32 + q * 8];

    unsigned int best[4][4];
    #pragma unroll
    for (int mt = 0; mt < 4; ++mt)
        #pragma unroll
        for (int r = 0; r < 4; ++r) best[mt][r] = 0xFFFFFFFFu;

    for (int ch = 0; ch < NCH; ++ch) {
        const int p = ch & 1;
        const unsigned char* bb = (const unsigned char*)bbuf[p];

        // (a) frag + norm LDS reads (swizzled addresses)
        bf16x8 bf[2][4];
        float en[2];
        #pragma unroll
        for (int nt = 0; nt < 2; ++nt) {
            const int r = wn * 32 + nt * 16 + nn;
            const unsigned int sx = (unsigned int)(r & 7) << 4;
            #pragma unroll
            for (int ks = 0; ks < 4; ++ks)
                bf[nt][ks] = *(const bf16x8*)(bb + (((unsigned int)r * 256u + ks * 64u + q * 16u) ^ sx));
            en[nt] = norm_lds[ch * CHK + wn * 32 + nt * 16 + nn];
        }
        // (b) my LDS reads retired -> safe to let others overwrite after barrier
        asm volatile("s_waitcnt lgkmcnt(0)" ::: "memory");
        __builtin_amdgcn_s_barrier();                 // A: all waves done reading bbuf[p]
        __builtin_amdgcn_sched_barrier(0);

        // (c) issue prefetch of chunk ch+2 into bbuf[p] (stays in flight across B)
        if (ch + 2 < NCH) {
            const unsigned char* src = img + (size_t)(ch + 2) * CHB;
            #pragma unroll
            for (int i = 0; i < 4; ++i) {
                int j = w * 4 + i;
                __builtin_amdgcn_global_load_lds(
                    (const __attribute__((address_space(1))) unsigned int*)(src + j * 1024 + lane * 16),
                    (__attribute__((address_space(3))) unsigned int*)((unsigned char*)bbuf[p] + j * 1024),
                    16, 0, 0);
            }
        }
        __builtin_amdgcn_sched_barrier(0);            // keep issues ahead of MFMA

        // (d) compute
        const unsigned int code0 = (unsigned int)(ch * CHK + wn * 32 + nn);
        f32x4 acc[4][2];
        #pragma unroll
        for (int mt = 0; mt < 4; ++mt)
            #pragma unroll
            for (int nt = 0; nt < 2; ++nt) acc[mt][nt] = (f32x4){0.f, 0.f, 0.f, 0.f};
        __builtin_amdgcn_s_setprio(1);
        #pragma unroll
        for (int ks = 0; ks < 4; ++ks)
            #pragma unroll
            for (int mt = 0; mt < 4; ++mt)
                #pragma unroll
                for (int nt = 0; nt < 2; ++nt)
                    acc[mt][nt] = __builtin_amdgcn_mfma_f32_16x16x32_bf16(a[mt][ks], bf[nt][ks], acc[mt][nt], 0, 0, 0);
        __builtin_amdgcn_s_setprio(0);

        // packed argmin: score' = (enorm+1) - 2*dot (always ~1.0 > 0),
        // clear low 10 mantissa bits, OR in code; u32 min == float min + tie-low.
        #pragma unroll
        for (int mt = 0; mt < 4; ++mt)
            #pragma unroll
            for (int r = 0; r < 4; ++r) {
                float s0 = fmaf(acc[mt][0][r], -2.0f, en[0]);
                float s1 = fmaf(acc[mt][1][r], -2.0f, en[1]);
                unsigned int u0 = (__float_as_uint(s0) & ~1023u) | code0;
                unsigned int u1 = (__float_as_uint(s1) & ~1023u) | (code0 + 16u);
                best[mt][r] = min(best[mt][r], min(u0, u1));
            }

        // (e) counted wait: ch+1's 4 loads (oldest) retired; ch+2's may fly on
        if (ch + 2 < NCH) {
            asm volatile("s_waitcnt vmcnt(4)" ::: "memory");
        } else {
            asm volatile("s_waitcnt vmcnt(0)" ::: "memory");
        }
        __builtin_amdgcn_s_barrier();                 // B: bbuf[p^1] valid for all
        __builtin_amdgcn_sched_barrier(0);
    }

    // in-wave reduce over the 16 code-columns (xor lanes 1,2,4,8 stay in quad)
    #pragma unroll
    for (int mt = 0; mt < 4; ++mt)
        #pragma unroll
        for (int r = 0; r < 4; ++r) {
            unsigned int v = best[mt][r];
            v = min(v, (unsigned int)__shfl_xor((int)v, 1));
            v = min(v, (unsigned int)__shfl_xor((int)v, 2));
            v = min(v, (unsigned int)__shfl_xor((int)v, 4));
            v = min(v, (unsigned int)__shfl_xor((int)v, 8));
            if (nn == 0) wbest[wn][wm * 64 + mt * 16 + q * 4 + r] = v;
        }
    __syncthreads();

    if (t < MB) {
        unsigned int v = min(wbest[0][t], wbest[1][t]);
        unsigned int code = v & 1023u;
        idxs[t] = (unsigned short)code;
        out[IDX_OFF + n0g + t] = (float)code;
    }
    __syncthreads();

    // epilogue: exact fp32 gather of chosen code rows, z_q store, loss
    {
        int pos = t & (MB - 1);
        int c0b = (t >> 7) * 64;
        int myidx = idxs[pos];
        const float* erow = emb + (size_t)myidx * C;
        float* og = out + ZQ_OFF + (size_t)b * C * HW + hw0;
        float ls = 0.f;
        #pragma unroll
        for (int i = 0; i < 16; ++i) {
            int c0 = c0b + i * 4;
            float4 ev = *(const float4*)&erow[c0];
            ushort4 zz = *(ushort4*)&zt[pos * RS + c0];
            float z0 = __uint_as_float((unsigned int)zz.x << 16);
            float z1 = __uint_as_float((unsigned int)zz.y << 16);
            float z2 = __uint_as_float((unsigned int)zz.z << 16);
            float z3 = __uint_as_float((unsigned int)zz.w << 16);
            float d0 = z0 - ev.x, d1 = z1 - ev.y, d2 = z2 - ev.z, d3 = z3 - ev.w;
            ls += d0 * d0 + d1 * d1 + d2 * d2 + d3 * d3;
            og[(size_t)(c0 + 0) * HW + pos] = ev.x;
            og[(size_t)(c0 + 1) * HW + pos] = ev.y;
            og[(size_t)(c0 + 2) * HW + pos] = ev.z;
            og[(size_t)(c0 + 3) * HW + pos] = ev.w;
        }
        #pragma unroll
        for (int off = 32; off; off >>= 1) ls += __shfl_down(ls, off);
        if (lane == 0) lred[w] = ls;
    }
    __syncthreads();
    if (t == 0) atomicAdd(S, lred[0] + lred[1] + lred[2] + lred[3]);
}

__global__ void vq_final(const float* __restrict__ S, float* __restrict__ out) {
    float s = *S;
    out[LOSS_OFF] = 1.25f * s;
    out[COMMIT_OFF] = 0.25f * s;
    out[CODE_OFF] = s;
}

extern "C" void kernel_launch(void* const* d_in, const int* in_sizes, int n_in,
                              void* d_out, int out_size, void* d_ws, size_t ws_size,
                              hipStream_t stream) {
    const float* z = (const float*)d_in[0];
    const float* emb = (const float*)d_in[1];
    float* out = (float*)d_out;
    float* S = (float*)d_ws;
    unsigned char* img = (unsigned char*)d_ws + WS_IMG_OFF;   // needs ~268 KB of ws

    vq_prep<<<K, 64, 0, stream>>>(emb, img, S);
    vq_main<<<NBLK, 256, 0, stream>>>(z, emb, img, out, S);
    vq_final<<<1, 1, 0, stream>>>(S, out);
}